// Round 2
// baseline (1206.438 us; speedup 1.0000x reference)
//
#include <hip/hip_runtime.h>
#include <math.h>

// GCN 2-layer + sigmoid head, CSR-gather formulation (no fp32 atomics):
//   deg[d]   = in-degree(d); dinv = rsqrt(deg+1)  (self-loop)
//   g1[i]    = (x[i] @ W1) * dinv[i]
//   agg1[d]  = g1[d] + sum_{(s->d)} g1[s]         (gather over dst-CSR)
//   t        = relu(dinv[d]*agg1[d] + b1);  g2[d] = (t @ W2) * dinv[d]
//   agg2[d]  = g2[d] + sum g2[s];  h = relu(dinv*agg2 + b2)
//   out      = sigmoid(h @ Wfc + bfc)

#define TPB 256
#define SCAN_ITEMS 8
#define SCAN_CHUNK (TPB * SCAN_ITEMS)  // 2048

__global__ void k_zero_i32(int* __restrict__ p, int n) {
    int i = blockIdx.x * blockDim.x + threadIdx.x;
    if (i < n) p[i] = 0;
}

__global__ void k_count(const int* __restrict__ dst, int* __restrict__ deg, int e) {
    int i = blockIdx.x * blockDim.x + threadIdx.x;
    if (i < e) atomicAdd(&deg[dst[i]], 1);
}

// per-chunk sums of deg
__global__ void k_blocksum(const int* __restrict__ deg, int* __restrict__ bsum, int n) {
    __shared__ int sm[TPB];
    int b = blockIdx.x, t = threadIdx.x;
    int base = b * SCAN_CHUNK + t * SCAN_ITEMS;
    int s = 0;
#pragma unroll
    for (int k = 0; k < SCAN_ITEMS; k++) {
        int i = base + k;
        if (i < n) s += deg[i];
    }
    sm[t] = s;
    __syncthreads();
    for (int off = TPB / 2; off > 0; off >>= 1) {
        if (t < off) sm[t] += sm[t + off];
        __syncthreads();
    }
    if (t == 0) bsum[b] = sm[0];
}

// exclusive scan of up to 256 chunk sums (single block)
__global__ void k_scantop(const int* __restrict__ bsum, int* __restrict__ boff, int nb) {
    __shared__ int sm[TPB];
    int t = threadIdx.x;
    int v = (t < nb) ? bsum[t] : 0;
    sm[t] = v;
    __syncthreads();
    for (int off = 1; off < TPB; off <<= 1) {
        int a = (t >= off) ? sm[t - off] : 0;
        __syncthreads();
        sm[t] += a;
        __syncthreads();
    }
    if (t < nb) boff[t] = sm[t] - v;  // exclusive
}

// cursor[i] = exclusive prefix of deg; dinv[i] = rsqrt(deg[i]+1)
__global__ void k_scanfinal(const int* __restrict__ deg, const int* __restrict__ boff,
                            int* __restrict__ cursor, float* __restrict__ dinv, int n) {
    __shared__ int sm[TPB];
    int b = blockIdx.x, t = threadIdx.x;
    int base = b * SCAN_CHUNK + t * SCAN_ITEMS;
    int v[SCAN_ITEMS];
    int s = 0;
#pragma unroll
    for (int k = 0; k < SCAN_ITEMS; k++) {
        int i = base + k;
        v[k] = (i < n) ? deg[i] : 0;
        s += v[k];
    }
    sm[t] = s;
    __syncthreads();
    for (int off = 1; off < TPB; off <<= 1) {
        int a = (t >= off) ? sm[t - off] : 0;
        __syncthreads();
        sm[t] += a;
        __syncthreads();
    }
    int thread_off = boff[b] + sm[t] - s;  // exclusive across threads
    int run = thread_off;
#pragma unroll
    for (int k = 0; k < SCAN_ITEMS; k++) {
        int i = base + k;
        if (i < n) {
            cursor[i] = run;
            dinv[i] = rsqrtf((float)(v[k] + 1));
            run += v[k];
        }
    }
}

// csr fill: pos = cursor[d]++; csr[pos] = s.  After this, cursor[i] == row end.
__global__ void k_fill(const int* __restrict__ src, const int* __restrict__ dst,
                       int* __restrict__ cursor, int* __restrict__ csr, int e) {
    int i = blockIdx.x * blockDim.x + threadIdx.x;
    if (i < e) {
        int s = src[i], d = dst[i];
        int pos = atomicAdd(&cursor[d], 1);
        csr[pos] = s;
    }
}

// g1[i] = (x[i] @ W1) * dinv[i]
__global__ void k_g1(const float* __restrict__ x, const float* __restrict__ W1,
                     const float* __restrict__ dinv, float* __restrict__ g1, int n) {
    __shared__ float w[96];  // 6 x 16
    if (threadIdx.x < 96) w[threadIdx.x] = W1[threadIdx.x];
    __syncthreads();
    int i = blockIdx.x * blockDim.x + threadIdx.x;
    if (i >= n) return;
    float xv[6];
#pragma unroll
    for (int k = 0; k < 6; k++) xv[k] = x[i * 6 + k];
    float di = dinv[i];
#pragma unroll
    for (int f = 0; f < 16; f++) {
        float h = 0.0f;
#pragma unroll
        for (int k = 0; k < 6; k++) h += xv[k] * w[k * 16 + f];
        g1[i * 16 + f] = h * di;
    }
}

// gather agg1 over CSR (+self), then fused: t = relu(dinv*agg1+b1); g2 = (t@W2)*dinv
__global__ void k_gather1(const float* __restrict__ g1, const int* __restrict__ csr,
                          const int* __restrict__ cursor, const int* __restrict__ deg,
                          const float* __restrict__ dinv, const float* __restrict__ b1,
                          const float* __restrict__ W2, float* __restrict__ g2, int n) {
    __shared__ float w[128];  // 16 x 8
    __shared__ float bb[16];
    if (threadIdx.x < 128) w[threadIdx.x] = W2[threadIdx.x];
    if (threadIdx.x < 16) bb[threadIdx.x] = b1[threadIdx.x];
    __syncthreads();
    int i = blockIdx.x * blockDim.x + threadIdx.x;
    if (i >= n) return;
    const float4* gv = (const float4*)g1;
    float acc[16];
    {
        float4 a0 = gv[i * 4 + 0], a1 = gv[i * 4 + 1], a2 = gv[i * 4 + 2], a3 = gv[i * 4 + 3];
        acc[0] = a0.x; acc[1] = a0.y; acc[2] = a0.z; acc[3] = a0.w;
        acc[4] = a1.x; acc[5] = a1.y; acc[6] = a1.z; acc[7] = a1.w;
        acc[8] = a2.x; acc[9] = a2.y; acc[10] = a2.z; acc[11] = a2.w;
        acc[12] = a3.x; acc[13] = a3.y; acc[14] = a3.z; acc[15] = a3.w;
    }
    int end = cursor[i];
    int start = end - deg[i];
    int j = start;
    for (; j + 1 < end; j += 2) {  // 2 independent gather chains for ILP
        int s0 = csr[j], s1 = csr[j + 1];
        float4 a0 = gv[s0 * 4 + 0], a1 = gv[s0 * 4 + 1], a2 = gv[s0 * 4 + 2], a3 = gv[s0 * 4 + 3];
        float4 c0 = gv[s1 * 4 + 0], c1 = gv[s1 * 4 + 1], c2 = gv[s1 * 4 + 2], c3 = gv[s1 * 4 + 3];
        acc[0] += a0.x + c0.x; acc[1] += a0.y + c0.y; acc[2] += a0.z + c0.z; acc[3] += a0.w + c0.w;
        acc[4] += a1.x + c1.x; acc[5] += a1.y + c1.y; acc[6] += a1.z + c1.z; acc[7] += a1.w + c1.w;
        acc[8] += a2.x + c2.x; acc[9] += a2.y + c2.y; acc[10] += a2.z + c2.z; acc[11] += a2.w + c2.w;
        acc[12] += a3.x + c3.x; acc[13] += a3.y + c3.y; acc[14] += a3.z + c3.z; acc[15] += a3.w + c3.w;
    }
    if (j < end) {
        int s0 = csr[j];
        float4 a0 = gv[s0 * 4 + 0], a1 = gv[s0 * 4 + 1], a2 = gv[s0 * 4 + 2], a3 = gv[s0 * 4 + 3];
        acc[0] += a0.x; acc[1] += a0.y; acc[2] += a0.z; acc[3] += a0.w;
        acc[4] += a1.x; acc[5] += a1.y; acc[6] += a1.z; acc[7] += a1.w;
        acc[8] += a2.x; acc[9] += a2.y; acc[10] += a2.z; acc[11] += a2.w;
        acc[12] += a3.x; acc[13] += a3.y; acc[14] += a3.z; acc[15] += a3.w;
    }
    float di = dinv[i];
    float t[16];
#pragma unroll
    for (int f = 0; f < 16; f++) t[f] = fmaxf(di * acc[f] + bb[f], 0.0f);
#pragma unroll
    for (int f2 = 0; f2 < 8; f2++) {
        float h = 0.0f;
#pragma unroll
        for (int f = 0; f < 16; f++) h += t[f] * w[f * 8 + f2];
        g2[i * 8 + f2] = h * di;
    }
}

// gather agg2 over CSR (+self), fused: h = relu(dinv*agg2+b2); out = sigmoid(h@Wfc+bfc)
__global__ void k_gather2(const float* __restrict__ g2, const int* __restrict__ csr,
                          const int* __restrict__ cursor, const int* __restrict__ deg,
                          const float* __restrict__ dinv, const float* __restrict__ b2,
                          const float* __restrict__ Wfc, const float* __restrict__ bfc,
                          float* __restrict__ out, int n) {
    __shared__ float w[8];
    __shared__ float bb[8];
    __shared__ float bf;
    if (threadIdx.x < 8) { w[threadIdx.x] = Wfc[threadIdx.x]; bb[threadIdx.x] = b2[threadIdx.x]; }
    if (threadIdx.x == 0) bf = bfc[0];
    __syncthreads();
    int i = blockIdx.x * blockDim.x + threadIdx.x;
    if (i >= n) return;
    const float4* gv = (const float4*)g2;
    float acc[8];
    {
        float4 a0 = gv[i * 2 + 0], a1 = gv[i * 2 + 1];
        acc[0] = a0.x; acc[1] = a0.y; acc[2] = a0.z; acc[3] = a0.w;
        acc[4] = a1.x; acc[5] = a1.y; acc[6] = a1.z; acc[7] = a1.w;
    }
    int end = cursor[i];
    int start = end - deg[i];
    int j = start;
    for (; j + 1 < end; j += 2) {
        int s0 = csr[j], s1 = csr[j + 1];
        float4 a0 = gv[s0 * 2 + 0], a1 = gv[s0 * 2 + 1];
        float4 c0 = gv[s1 * 2 + 0], c1 = gv[s1 * 2 + 1];
        acc[0] += a0.x + c0.x; acc[1] += a0.y + c0.y; acc[2] += a0.z + c0.z; acc[3] += a0.w + c0.w;
        acc[4] += a1.x + c1.x; acc[5] += a1.y + c1.y; acc[6] += a1.z + c1.z; acc[7] += a1.w + c1.w;
    }
    if (j < end) {
        int s0 = csr[j];
        float4 a0 = gv[s0 * 2 + 0], a1 = gv[s0 * 2 + 1];
        acc[0] += a0.x; acc[1] += a0.y; acc[2] += a0.z; acc[3] += a0.w;
        acc[4] += a1.x; acc[5] += a1.y; acc[6] += a1.z; acc[7] += a1.w;
    }
    float di = dinv[i];
    float o = bf;
#pragma unroll
    for (int f = 0; f < 8; f++) {
        float h = fmaxf(di * acc[f] + bb[f], 0.0f);
        o += h * w[f];
    }
    out[i] = 1.0f / (1.0f + expf(-o));
}

extern "C" void kernel_launch(void* const* d_in, const int* in_sizes, int n_in,
                              void* d_out, int out_size, void* d_ws, size_t ws_size,
                              hipStream_t stream) {
    const float* x   = (const float*)d_in[0];
    const int*   ei  = (const int*)d_in[1];
    const float* W1  = (const float*)d_in[2];
    const float* b1  = (const float*)d_in[3];
    const float* W2  = (const float*)d_in[4];
    const float* b2  = (const float*)d_in[5];
    const float* Wfc = (const float*)d_in[6];
    const float* bfc = (const float*)d_in[7];
    float* out = (float*)d_out;

    const int n = in_sizes[0] / 6;   // 200000
    const int e = in_sizes[1] / 2;   // 6400000
    const int* src = ei;
    const int* dst = ei + e;

    // workspace layout (all 64B-aligned given 256B-aligned d_ws)
    int* deg    = (int*)d_ws;            // n
    int* cursor = deg + n;               // n
    int* csr    = cursor + n;            // e
    int* bsum   = csr + e;               // 256
    int* boff   = bsum + 256;            // 256
    float* dinv = (float*)(boff + 256);  // n
    float* g1   = dinv + n;              // 16n
    float* g2   = g1 + 16 * (size_t)n;   // 8n

    int gn = (n + TPB - 1) / TPB;
    int ge = (e + TPB - 1) / TPB;
    int nb = (n + SCAN_CHUNK - 1) / SCAN_CHUNK;  // 98 chunks for n=200k (<=256)

    k_zero_i32<<<gn, TPB, 0, stream>>>(deg, n);
    k_count<<<ge, TPB, 0, stream>>>(dst, deg, e);
    k_blocksum<<<nb, TPB, 0, stream>>>(deg, bsum, n);
    k_scantop<<<1, TPB, 0, stream>>>(bsum, boff, nb);
    k_scanfinal<<<nb, TPB, 0, stream>>>(deg, boff, cursor, dinv, n);
    k_g1<<<gn, TPB, 0, stream>>>(x, W1, dinv, g1, n);
    k_fill<<<ge, TPB, 0, stream>>>(src, dst, cursor, csr, e);
    k_gather1<<<gn, TPB, 0, stream>>>(g1, csr, cursor, deg, dinv, b1, W2, g2, n);
    k_gather2<<<gn, TPB, 0, stream>>>(g2, csr, cursor, deg, dinv, b2, Wfc, bfc, out, n);
}